// Round 16
// baseline (218.667 us; speedup 1.0000x reference)
//
#include <hip/hip_runtime.h>

// TwoLayerSNN forward: B=256, T=1000, D=32, H=200, O=2
// Round 16 = round 15 (passing, 182us) with the per-step DPP reduction moved
// OFF the consumer wave. Roles (block 832 = 13 waves):
//   w0-3  consumers: recurrence + global stores + ds_write of s1v (short chain)
//   w4-7  producers: dots for sub-chunk sc+1 (r15 text, prefetch kept)
//   w8-11 reducers:  lag 1; read s1ls, per-lane 4-h fma + full DPP tree,
//                    5 timesteps per wave -> partq
//   w12   layer-2:   lag 2; pk-packed serial chain from partq (r14 math)
// s1 products are EXACT (s1 in {0,1}) -> any summation order is exact adds;
// only association changes vs r15. All LDS handoffs parity-dbuf +
// barrier-separated (audited).

constexpr int TB = 256;
constexpr int TT = 1000;
constexpr int DD = 32;
constexpr int HH = 200;
constexpr int OO = 2;
constexpr int CH = 40;                    // timesteps per x staging chunk (5 KB)
constexpr int NCH = TT / CH;              // 25
constexpr int SC = 20;                    // timesteps per barrier interval
constexpr int NSC = TT / SC;              // 50
constexpr int XF4 = CH * DD / 4;          // 320 float4 per chunk

typedef float v2f __attribute__((ext_vector_type(2)));

__device__ __forceinline__ v2f pk_fma(v2f a, v2f b, v2f c) {
#if __has_builtin(__builtin_elementwise_fma)
    return __builtin_elementwise_fma(a, b, c);
#else
    v2f r; r.x = fmaf(a.x, b.x, c.x); r.y = fmaf(a.y, b.y, c.y); return r;
#endif
}

template <int CTRL>
__device__ __forceinline__ float dpp_add(float v) {
    int t = __builtin_amdgcn_update_dpp(0, __float_as_int(v), CTRL, 0xf, 0xf, true);
    return v + __int_as_float(t);
}

__device__ __forceinline__ void wave_sum2(float& a, float& b) {
    // full wave64 sum; result valid in lane 63. (verified r2/r6-r10)
    a = dpp_add<0x111>(a); b = dpp_add<0x111>(b);
    a = dpp_add<0x112>(a); b = dpp_add<0x112>(b);
    a = dpp_add<0x114>(a); b = dpp_add<0x114>(b);
    a = dpp_add<0x118>(a); b = dpp_add<0x118>(b);
    a = dpp_add<0x142>(a); b = dpp_add<0x142>(b);
    a = dpp_add<0x143>(a); b = dpp_add<0x143>(b);
}

__device__ __forceinline__ void block_sync_lds() {
    // Order LDS only (validated r8-r15): drain lgkm, raw barrier.
    asm volatile("s_waitcnt lgkmcnt(0)" ::: "memory");
    __builtin_amdgcn_s_barrier();
    asm volatile("" ::: "memory");
}

__global__ __launch_bounds__(832, 1)
void snn_fwd(const float* __restrict__ x,
             const float* __restrict__ w1,
             const float* __restrict__ w2,
             float* __restrict__ out)
{
    const int b    = blockIdx.x;
    const int tid  = threadIdx.x;
    const int lane = tid & 63;
    const int wid  = tid >> 6;
    const bool is_cons = (wid < 4);              // waves 0-3
    const bool is_prod = (wid >= 4 && wid < 8);  // waves 4-7
    const bool is_red  = (wid >= 8 && wid < 12); // waves 8-11
    const bool is_l2   = (wid == 12);            // wave 12
    const int ptid = tid - 256;                  // producer-local 0..255
    const bool act = is_cons && (tid < HH);

    float* __restrict__ outp = out;                        // [TB][OO]
    float* __restrict__ s1o  = out + (size_t)TB * OO;      // [TB][TT][HH]
    float* __restrict__ m1o  = s1o + (size_t)TB * TT * HH; // [TB][TT][HH]
    float* __restrict__ s2o  = m1o + (size_t)TB * TT * HH; // [TB][TT][OO]
    float* __restrict__ m2o  = s2o + (size_t)TB * TT * OO; // [TB][TT][OO]

    const float A_SYN1 = (float)0.8187307530779818;
    const float IN_SC1 = (float)((1.0 - 0.8187307530779818) * 5.0);
    const float A_MEM1 = (float)0.9048374180359595;
    const float B_MEM1 = (float)(1.0 - 0.9048374180359595);
    const float TH1    = 0.5f;
    const float A_SYN2 = (float)0.9048374180359595;
    const float IN_SC2 = (float)((1.0 - 0.9048374180359595) * 10.0);
    const float A_MEM2 = (float)0.9512294245007140;
    const float B_MEM2 = (float)(1.0 - 0.9512294245007140);
    const float TH2    = 1.0f;

    __shared__ float4 xls[2][XF4];                 // 2 x 5 KB
    __shared__ float  dotb[2][SC][HH];             // 2 x 16 KB
    __shared__ float  s1ls[2][SC][HH];             // 2 x 16 KB
    __shared__ __align__(8) float2 partq[2][SC];   // reducer -> L2, 320 B

    const float* __restrict__ xb = x + (size_t)b * TT * DD;

    // producer: 50 hidden units per wave; w1 column as 16 float2 pairs
    const int ph   = (wid - 4) * 50 + lane;
    const bool pact = is_prod && (lane < 50);
    v2f w1e[DD / 4], w1o[DD / 4];
#pragma unroll
    for (int i = 0; i < DD / 4; ++i) {
        w1e[i] = pact ? v2f{w1[(4 * i) * HH + ph],     w1[(4 * i + 1) * HH + ph]} : v2f{0.f, 0.f};
        w1o[i] = pact ? v2f{w1[(4 * i + 2) * HH + ph], w1[(4 * i + 3) * HH + ph]} : v2f{0.f, 0.f};
    }
    // reducer: w2 values for h = lane + 64k (k=0..3)
    float w2xa[4], w2ya[4];
#pragma unroll
    for (int k = 0; k < 4; ++k) {
        const int h = lane + 64 * k;
        const bool v = is_red && (h < HH);
        w2xa[k] = v ? w2[h * OO + 0] : 0.0f;
        w2ya[k] = v ? w2[h * OO + 1] : 0.0f;
    }

    // stage chunk 0 (5 KB, 320 float4) using consumer threads (one-time)
    if (is_cons) {
        const float4* g = (const float4*)xb;
        if (2 * tid     < XF4) xls[0][2 * tid]     = g[2 * tid];
        if (2 * tid + 1 < XF4) xls[0][2 * tid + 1] = g[2 * tid + 1];
    }
    block_sync_lds();

    // produce(j): dots for sub-chunk j into dotb[j&1] (r15 text, verified)
    auto produce = [&](int j) {
        const float4* xq = &xls[(j >> 1) & 1][(j & 1) * SC * (DD / 4)];
        float4 Xc0 = xq[0], Xc1 = xq[1], Xc2 = xq[2], Xc3 = xq[3];
        float4 Xc4 = xq[4], Xc5 = xq[5], Xc6 = xq[6], Xc7 = xq[7];
#pragma unroll
        for (int s = 0; s < SC; ++s) {
            float4 Xn0, Xn1, Xn2, Xn3, Xn4, Xn5, Xn6, Xn7;
            if (s < SC - 1) {
                const float4* nq = xq + (s + 1) * 8;
                Xn0 = nq[0]; Xn1 = nq[1]; Xn2 = nq[2]; Xn3 = nq[3];
                Xn4 = nq[4]; Xn5 = nq[5]; Xn6 = nq[6]; Xn7 = nq[7];
            }
            v2f A01 = {0.f, 0.f}, A23 = {0.f, 0.f};
            A01 = pk_fma(v2f{Xc0.x, Xc0.y}, w1e[0], A01);
            A23 = pk_fma(v2f{Xc0.z, Xc0.w}, w1o[0], A23);
            A01 = pk_fma(v2f{Xc1.x, Xc1.y}, w1e[1], A01);
            A23 = pk_fma(v2f{Xc1.z, Xc1.w}, w1o[1], A23);
            A01 = pk_fma(v2f{Xc2.x, Xc2.y}, w1e[2], A01);
            A23 = pk_fma(v2f{Xc2.z, Xc2.w}, w1o[2], A23);
            A01 = pk_fma(v2f{Xc3.x, Xc3.y}, w1e[3], A01);
            A23 = pk_fma(v2f{Xc3.z, Xc3.w}, w1o[3], A23);
            A01 = pk_fma(v2f{Xc4.x, Xc4.y}, w1e[4], A01);
            A23 = pk_fma(v2f{Xc4.z, Xc4.w}, w1o[4], A23);
            A01 = pk_fma(v2f{Xc5.x, Xc5.y}, w1e[5], A01);
            A23 = pk_fma(v2f{Xc5.z, Xc5.w}, w1o[5], A23);
            A01 = pk_fma(v2f{Xc6.x, Xc6.y}, w1e[6], A01);
            A23 = pk_fma(v2f{Xc6.z, Xc6.w}, w1o[6], A23);
            A01 = pk_fma(v2f{Xc7.x, Xc7.y}, w1e[7], A01);
            A23 = pk_fma(v2f{Xc7.z, Xc7.w}, w1o[7], A23);
            const float dotv = __fadd_rn(__fadd_rn(A01.x, A01.y),
                                         __fadd_rn(A23.x, A23.y));
            if (pact) dotb[j & 1][s][ph] = dotv;
            if (s < SC - 1) {
                Xc0 = Xn0; Xc1 = Xn1; Xc2 = Xn2; Xc3 = Xn3;
                Xc4 = Xn4; Xc5 = Xn5; Xc6 = Xn6; Xc7 = Xn7;
            }
        }
    };

    // prologue: fill dotb[0]
    if (is_prod) produce(0);
    block_sync_lds();

    float syn1 = 0.0f, mem1 = 0.0f;
    double accx = 0.0, accy = 0.0;
    v2f syn2 = {0.f, 0.f}, mem2 = {0.f, 0.f};
    const v2f A2v  = {A_SYN2, A_SYN2};
    const v2f SC2v = {IN_SC2, IN_SC2};
    const v2f AM2v = {A_MEM2, A_MEM2};
    const v2f BM2v = {B_MEM2, B_MEM2};
    const v2f TH2v = {TH2, TH2};

    float* __restrict__ s1p = s1o + (size_t)b * TT * HH + tid;
    float* __restrict__ m1p = m1o + (size_t)b * TT * HH + tid;
    float2* __restrict__ s2p = (float2*)(s2o + (size_t)b * TT * OO);
    float2* __restrict__ m2p = (float2*)(m2o + (size_t)b * TT * OO);

    // reducer: layer-2 drive sums for sub-chunk j (5 steps per wave)
    auto reduce_chunk = [&](int j) {
        const int rw = wid - 8;
#pragma unroll
        for (int q = 0; q < 5; ++q) {
            const int s = rw * 5 + q;
            const float* sp = &s1ls[j & 1][s][0];
            float cx = 0.0f, cy = 0.0f;
#pragma unroll
            for (int k = 0; k < 4; ++k) {
                const int h = lane + 64 * k;
                const float sv = (h < HH) ? sp[h] : 0.0f;
                cx = fmaf(sv, w2xa[k], cx);   // exact products: s1 in {0,1}
                cy = fmaf(sv, w2ya[k], cy);
            }
            wave_sum2(cx, cy);
            if (lane == 63) partq[j & 1][s] = make_float2(cx, cy);
        }
    };

    // wave 12: layer-2 serial chain for sub-chunk j (r14 pk math)
    auto l2_chunk = [&](int j) {
#pragma clang fp contract(off)
        float2 P[SC];
#pragma unroll
        for (int s = 0; s < SC; ++s) P[s] = partq[j & 1][s];
#pragma unroll
        for (int s = 0; s < SC; ++s) {
            const v2f d = {P[s].x, P[s].y};
            syn2 = (A2v * syn2) + (SC2v * d);
            mem2 = (AM2v * mem2) + (BM2v * syn2);
            const float s2x = (mem2.x - TH2 > 0.0f) ? 1.0f : 0.0f;
            const float s2y = (mem2.y - TH2 > 0.0f) ? 1.0f : 0.0f;
            const v2f s2v = {s2x, s2y};
            mem2 = mem2 - (s2v * TH2v);
            const int t = j * SC + s;
            if (tid == 768) {
                s2p[t] = make_float2(s2x, s2y);
                m2p[t] = make_float2(mem2.x, mem2.y);
            }
            if (t > 0) { accx += (double)mem2.x; accy += (double)mem2.y; }
        }
    };

    for (int sc = 0; sc < NSC; ++sc) {
        const int t0   = sc * SC;
        const int c    = t0 / CH;
        const int cpos = t0 % CH;

        if (is_cons) {
            // ---- consumer: dots from LDS; recurrence + stores only ----
            float D[SC];
#pragma unroll
            for (int s = 0; s < SC; ++s) D[s] = dotb[sc & 1][s][tid];

#pragma unroll
            for (int s = 0; s < SC; ++s) {
                const float dot = D[s];
                syn1 = __fadd_rn(__fmul_rn(A_SYN1, syn1), __fmul_rn(IN_SC1, dot));
                mem1 = __fadd_rn(__fmul_rn(A_MEM1, mem1), __fmul_rn(B_MEM1, syn1));
                const float s1v = (mem1 - TH1 > 0.0f) ? 1.0f : 0.0f;
                mem1 = __fsub_rn(mem1, __fmul_rn(s1v, TH1));

                if (act) {
                    s1p[(size_t)(t0 + s) * HH] = s1v;
                    m1p[(size_t)(t0 + s) * HH] = mem1;
                    s1ls[sc & 1][s][tid] = s1v;
                }
            }
        } else if (is_prod) {
            // ---- producer: stage next chunk; dots for sub-chunk sc+1 ----
            float4 pr0, pr1;
            const bool stage = (cpos == 0 && c + 1 < NCH);
            if (stage) {
                const float4* g = (const float4*)(xb + (size_t)(c + 1) * CH * DD);
                if (2 * ptid     < XF4) pr0 = g[2 * ptid];
                if (2 * ptid + 1 < XF4) pr1 = g[2 * ptid + 1];
            }

            if (sc + 1 < NSC) produce(sc + 1);

            if (stage) {
                if (2 * ptid     < XF4) xls[(c + 1) & 1][2 * ptid]     = pr0;
                if (2 * ptid + 1 < XF4) xls[(c + 1) & 1][2 * ptid + 1] = pr1;
            }
        } else if (is_red) {
            // ---- reducers: layer-2 drive for sub-chunk sc-1 ----
            if (sc > 0) reduce_chunk(sc - 1);
        } else {
            // ---- wave 12: layer-2 chain for sub-chunk sc-2 ----
            if (sc > 1) l2_chunk(sc - 2);
        }

        block_sync_lds();
    }

    // epilogue A: reducers finish NSC-1; L2 does NSC-2
    if (is_red) reduce_chunk(NSC - 1);
    if (is_l2)  l2_chunk(NSC - 2);
    block_sync_lds();
    // epilogue B: L2 finishes NSC-1 and writes the mean output
    if (is_l2) {
        l2_chunk(NSC - 1);
        if (tid == 768) {
            outp[b * OO + 0] = (float)accx / 1000.0f;
            outp[b * OO + 1] = (float)accy / 1000.0f;
        }
    }
}

extern "C" void kernel_launch(void* const* d_in, const int* in_sizes, int n_in,
                              void* d_out, int out_size, void* d_ws, size_t ws_size,
                              hipStream_t stream) {
    const float* x  = (const float*)d_in[0];   // [256,1000,32]
    const float* w1 = (const float*)d_in[1];   // [32,200]
    const float* w2 = (const float*)d_in[2];   // [200,2]
    float* out = (float*)d_out;

    dim3 grid(TB), block(832);
    hipLaunchKernelGGL(snn_fwd, grid, block, 0, stream, x, w1, w2, out);
}